// Round 7
// baseline (54.433 us; speedup 1.0000x reference)
//
#include <hip/hip_runtime.h>

#define NCH 1024      // OUT_CH * IN_GROUP
#define KHW 64        // H*W = GEMM K
#define BPT 128       // points per tile   (MFMA n)
#define BCH 128       // channels per block (MFMA m)
#define NT  4         // point-tiles per block (pipelined)
#define WST 72        // W_lds row stride in bf16 (144 B, bank-staggered, 16B-aligned)
#define CST 72        // C_lds row stride in bf16

typedef __attribute__((ext_vector_type(8))) short          bf16x8;
typedef __attribute__((ext_vector_type(4))) float          f32x4;
typedef __attribute__((ext_vector_type(4))) int            i32x4;
typedef __attribute__((ext_vector_type(4))) unsigned short u16x4;

__device__ __forceinline__ unsigned short f2bf(float f) {
    unsigned int u = __float_as_uint(f);
    u += 0x7FFFu + ((u >> 16) & 1u);          // round-to-nearest-even
    return (unsigned short)(u >> 16);
}

__global__ __launch_bounds__(512)
void spline_gemm(const float* __restrict__ xy,
                 const float* __restrict__ C,
                 const float* __restrict__ Tx,
                 const float* __restrict__ Ty,
                 float* __restrict__ out,
                 int npts, int ntx, int nty, int nrep) {
    __shared__ __align__(16) unsigned short Cl[BCH * CST];      // 18 KB C slice (bf16)
    __shared__ __align__(16) unsigned short Wl[2][BPT * WST];   // 2 x 18 KB point weights

    const int t     = threadIdx.x;
    const int cgrp  = blockIdx.x & 7;      // 8 channel groups -> XCD-pinned
    const int pgrp  = blockIdx.x >> 3;     // 32 point groups of NT*BPT = 512 points
    const int pbase = pgrp * (NT * BPT);
    const int cbase = cgrp * BCH;

    // ---- stage C slice (128 ch x 64 k, contiguous 8192 floats) -> bf16 LDS ----
    const float* Cb = C + (size_t)cbase * KHW;
    #pragma unroll
    for (int r = 0; r < 4; ++r) {
        const int fi = r * 2048 + t * 4;
        f32x4 v = *(const f32x4*)(Cb + fi);
        const int ch = fi >> 6, k = fi & 63;
        u16x4 w;
        w.x = f2bf(v.x); w.y = f2bf(v.y); w.z = f2bf(v.z); w.w = f2bf(v.w);
        *(u16x4*)&Cl[ch * CST + k] = w;
    }

    // ---- per-point weight computation (threads 0..127), self-zeroing row ----
    auto weights = [&](int tile, int buf) {
        if (t < BPT) {
            const int n = pbase + tile * BPT + t;
            float X = 0.f, Y = 0.f;
            if (n < npts) {
                float2 p = *(const float2*)(xy + 2 * n);
                X = p.x; Y = p.y;
            }

            // kx = 2 + #{interior knots <= X}; knots are wave-uniform (SGPR loads)
            int kx = 2;
            for (int i = 3; i <= ntx - 4; ++i) kx += (Tx[i] <= X) ? 1 : 0;
            int ky = 2;
            for (int i = 3; i <= nty - 4; ++i) ky += (Ty[i] <= Y) ? 1 : 0;

            float tkm1 = Tx[kx - 1], tk = Tx[kx], tk1 = Tx[kx + 1], tk2 = Tx[kx + 2];
            float d;
            d = tk1 - tkm1; float a10 = (X - tkm1) / (d == 0.f ? 1.f : d);
            d = tk2 - tk;   float a11 = (X - tk)   / (d == 0.f ? 1.f : d);
            d = tk1 - tk;   float a21 = (X - tk)   / (d == 0.f ? 1.f : d);
            float wx0 = (1.f - a21) * (1.f - a10);
            float wx1 = (1.f - a21) * a10 + a21 * (1.f - a11);
            float wx2 = a21 * a11;

            tkm1 = Ty[ky - 1]; tk = Ty[ky]; tk1 = Ty[ky + 1]; tk2 = Ty[ky + 2];
            d = tk1 - tkm1; float b10 = (Y - tkm1) / (d == 0.f ? 1.f : d);
            d = tk2 - tk;   float b11 = (Y - tk)   / (d == 0.f ? 1.f : d);
            d = tk1 - tk;   float b21 = (Y - tk)   / (d == 0.f ? 1.f : d);
            float wy0 = (1.f - b21) * (1.f - b10);
            float wy1 = (1.f - b21) * b10 + b21 * (1.f - b11);
            float wy2 = b21 * b11;

            // zero own row (64 k-entries = 8 x 16B), then scatter 9 taps
            unsigned short* rowbase = &Wl[buf][t * WST];
            i32x4 z = {0, 0, 0, 0};
            #pragma unroll
            for (int j = 0; j < 8; ++j) *(i32x4*)(rowbase + j * 8) = z;

            unsigned short* row = rowbase + (kx - 2) * 8 + (ky - 2);
            row[0]  = f2bf(wx0 * wy0); row[1]  = f2bf(wx0 * wy1); row[2]  = f2bf(wx0 * wy2);
            row[8]  = f2bf(wx1 * wy0); row[9]  = f2bf(wx1 * wy1); row[10] = f2bf(wx1 * wy2);
            row[16] = f2bf(wx2 * wy0); row[17] = f2bf(wx2 * wy1); row[18] = f2bf(wx2 * wy2);
        }
    };

    // ---- 8 waves: wm = ch half (64), wn = pt quarter (32) ----
    const int wid  = t >> 6;
    const int lane = t & 63;
    const int wm   = wid & 1;
    const int wn   = wid >> 1;         // 0..3
    const int l15  = lane & 15;
    const int l4   = lane >> 4;

    const unsigned short* Ab = Cl + (wm * 64 + l15) * CST + l4 * 8;

    // DIAGNOSTIC: nrep=4 identical passes. Output identical & deterministic;
    // dur ~54us lifts this dispatch into rocprof's top-5 so we finally read
    // its FETCH_SIZE / WRITE_SIZE and split RFO-traffic vs launch-overhead.
    for (int rep = 0; rep < nrep; ++rep) {
        weights(0, 0);
        __syncthreads();

        for (int tile = 0; tile < NT; ++tile) {
            const int buf = tile & 1;
            const unsigned short* Bb = Wl[buf] + (wn * 32 + l15) * WST + l4 * 8;

            f32x4 acc[4][2] = {};
            #pragma unroll
            for (int kr = 0; kr < 2; ++kr) {
                bf16x8 a[4], b[2];
                #pragma unroll
                for (int mf = 0; mf < 4; ++mf) a[mf] = *(const bf16x8*)(Ab + mf * 16 * CST + kr * 32);
                #pragma unroll
                for (int nf = 0; nf < 2; ++nf) b[nf] = *(const bf16x8*)(Bb + nf * 16 * WST + kr * 32);
                #pragma unroll
                for (int mf = 0; mf < 4; ++mf)
                    #pragma unroll
                    for (int nf = 0; nf < 2; ++nf)
                        acc[mf][nf] = __builtin_amdgcn_mfma_f32_16x16x32_bf16(
                                          a[mf], b[nf], acc[mf][nf], 0, 0, 0);
            }

            // stores: D row=(lane>>4)*4+reg = 4 consecutive channels -> dwordx4
            #pragma unroll
            for (int nf = 0; nf < 2; ++nf) {
                const int pt = pbase + tile * BPT + wn * 32 + nf * 16 + l15;
                float* op = out + (size_t)pt * NCH + cbase + wm * 64 + l4 * 4;
                if (pt < npts) {
                    #pragma unroll
                    for (int mf = 0; mf < 4; ++mf)
                        *(f32x4*)(op + mf * 16) = acc[mf][nf];
                }
            }

            // next tile's weights into the other buffer (overlaps store drain)
            if (tile + 1 < NT) weights(tile + 1, buf ^ 1);
            __syncthreads();
        }
    }
}

extern "C" void kernel_launch(void* const* d_in, const int* in_sizes, int n_in,
                              void* d_out, int out_size, void* d_ws, size_t ws_size,
                              hipStream_t stream) {
    const float* xy = (const float*)d_in[0];
    const float* C  = (const float*)d_in[1];
    const float* Tx = (const float*)d_in[2];
    const float* Ty = (const float*)d_in[3];
    float* out = (float*)d_out;

    int npts = in_sizes[0] / 2;
    int ntx  = in_sizes[2];
    int nty  = in_sizes[3];

    int pgs = (npts + NT * BPT - 1) / (NT * BPT);
    dim3 grid(pgs * 8);
    dim3 block(512);
    hipLaunchKernelGGL(spline_gemm, grid, block, 0, stream,
                       xy, C, Tx, Ty, out, npts, ntx, nty, 4 /* nrep: diagnostic */);
}

// Round 8
// 19.745 us; speedup vs baseline: 2.7568x; 2.7568x over previous
//
#include <hip/hip_runtime.h>

#define NCH 1024      // OUT_CH * IN_GROUP
#define KHW 64        // H*W = GEMM K
#define BPT 128       // points per MFMA tile
#define BCH 128       // channels per block
#define NT  2         // point-tiles per block (256 points/block)
#define WST 72        // W_lds row stride in bf16 (144 B, 16B-aligned)
#define CST 72        // C_lds row stride in bf16

typedef __attribute__((ext_vector_type(8))) short          bf16x8;
typedef __attribute__((ext_vector_type(4))) float          f32x4;
typedef __attribute__((ext_vector_type(4))) int            i32x4;
typedef __attribute__((ext_vector_type(4))) unsigned short u16x4;

__device__ __forceinline__ unsigned short f2bf(float f) {
    unsigned int u = __float_as_uint(f);
    u += 0x7FFFu + ((u >> 16) & 1u);          // round-to-nearest-even
    return (unsigned short)(u >> 16);
}

__global__ __launch_bounds__(256)
void spline_gemm(const float* __restrict__ xy,
                 const float* __restrict__ C,
                 const float* __restrict__ Tx,
                 const float* __restrict__ Ty,
                 float* __restrict__ out,
                 int npts, int ntx, int nty) {
    __shared__ __align__(16) unsigned short Cl[BCH * CST];       // 18 KB C slice (bf16)
    __shared__ __align__(16) unsigned short Wl[NT][BPT * WST];   // 36 KB point weights

    const int t     = threadIdx.x;
    const int cgrp  = blockIdx.x & 7;      // 8 channel groups -> XCD-pinned
    const int pgrp  = blockIdx.x >> 3;     // 64 point groups of 256 points
    const int pbase = pgrp * (NT * BPT);
    const int cbase = cgrp * BCH;

    // ---- per-point weights: ONE point per thread, fully parallel ----
    {
        const int n  = pbase + t;
        const int nc = min(n, npts - 1);
        float2 p = *(const float2*)(xy + 2 * nc);
        float X = p.x, Y = p.y;

        // stage C slice (128 ch x 64 k = 8192 floats, 32/thread) -> bf16 LDS
        const float* Cb = C + (size_t)cbase * KHW;
        #pragma unroll
        for (int r = 0; r < 8; ++r) {
            const int fi = r * 1024 + t * 4;
            f32x4 v = *(const f32x4*)(Cb + fi);
            const int ch = fi >> 6, k = fi & 63;
            u16x4 w;
            w.x = f2bf(v.x); w.y = f2bf(v.y); w.z = f2bf(v.z); w.w = f2bf(v.w);
            *(u16x4*)&Cl[ch * CST + k] = w;
        }

        // knot interval: kx = 2 + #{interior knots <= X}
        int kx = 2;
        for (int i = 3; i <= ntx - 4; ++i) kx += (Tx[i] <= X) ? 1 : 0;
        int ky = 2;
        for (int i = 3; i <= nty - 4; ++i) ky += (Ty[i] <= Y) ? 1 : 0;

        float tkm1 = Tx[kx - 1], tk = Tx[kx], tk1 = Tx[kx + 1], tk2 = Tx[kx + 2];
        float d;
        d = tk1 - tkm1; float a10 = (X - tkm1) / (d == 0.f ? 1.f : d);
        d = tk2 - tk;   float a11 = (X - tk)   / (d == 0.f ? 1.f : d);
        d = tk1 - tk;   float a21 = (X - tk)   / (d == 0.f ? 1.f : d);
        float wx0 = (1.f - a21) * (1.f - a10);
        float wx1 = (1.f - a21) * a10 + a21 * (1.f - a11);
        float wx2 = a21 * a11;

        tkm1 = Ty[ky - 1]; tk = Ty[ky]; tk1 = Ty[ky + 1]; tk2 = Ty[ky + 2];
        d = tk1 - tkm1; float b10 = (Y - tkm1) / (d == 0.f ? 1.f : d);
        d = tk2 - tk;   float b11 = (Y - tk)   / (d == 0.f ? 1.f : d);
        d = tk1 - tk;   float b21 = (Y - tk)   / (d == 0.f ? 1.f : d);
        float wy0 = (1.f - b21) * (1.f - b10);
        float wy1 = (1.f - b21) * b10 + b21 * (1.f - b11);
        float wy2 = b21 * b11;

        // zero own row (8 x 16B) then scatter the 9 taps
        unsigned short* rowbase = &Wl[t >> 7][(t & 127) * WST];
        i32x4 z = {0, 0, 0, 0};
        #pragma unroll
        for (int j = 0; j < 8; ++j) *(i32x4*)(rowbase + j * 8) = z;

        unsigned short* row = rowbase + (kx - 2) * 8 + (ky - 2);
        row[0]  = f2bf(wx0 * wy0); row[1]  = f2bf(wx0 * wy1); row[2]  = f2bf(wx0 * wy2);
        row[8]  = f2bf(wx1 * wy0); row[9]  = f2bf(wx1 * wy1); row[10] = f2bf(wx1 * wy2);
        row[16] = f2bf(wx2 * wy0); row[17] = f2bf(wx2 * wy1); row[18] = f2bf(wx2 * wy2);
    }
    __syncthreads();   // the ONLY barrier

    // ---- 4 waves: wm = ch half (64), wn = pt half (64); 16 MFMA + 16 stores/tile ----
    const int wid  = t >> 6;
    const int lane = t & 63;
    const int wm   = wid & 1;
    const int wn   = wid >> 1;
    const int l15  = lane & 15;
    const int l4   = lane >> 4;

    const unsigned short* Ab = Cl + (wm * 64 + l15) * CST + l4 * 8;

    #pragma unroll
    for (int tile = 0; tile < NT; ++tile) {
        const unsigned short* Bb = Wl[tile] + (wn * 64 + l15) * WST + l4 * 8;

        f32x4 acc[4][4] = {};
        #pragma unroll
        for (int kr = 0; kr < 2; ++kr) {
            bf16x8 a[4], b[4];
            #pragma unroll
            for (int mf = 0; mf < 4; ++mf) a[mf] = *(const bf16x8*)(Ab + mf * 16 * CST + kr * 32);
            #pragma unroll
            for (int nf = 0; nf < 4; ++nf) b[nf] = *(const bf16x8*)(Bb + nf * 16 * WST + kr * 32);
            #pragma unroll
            for (int mf = 0; mf < 4; ++mf)
                #pragma unroll
                for (int nf = 0; nf < 4; ++nf)
                    acc[mf][nf] = __builtin_amdgcn_mfma_f32_16x16x32_bf16(
                                      a[mf], b[nf], acc[mf][nf], 0, 0, 0);
        }

        // stores: lane's 4 acc regs = 4 consecutive channels -> dwordx4
        #pragma unroll
        for (int nf = 0; nf < 4; ++nf) {
            const int pt = pbase + tile * BPT + wn * 64 + nf * 16 + l15;
            float* op = out + (size_t)pt * NCH + cbase + wm * 64 + l4 * 4;
            if (pt < npts) {
                #pragma unroll
                for (int mf = 0; mf < 4; ++mf)
                    *(f32x4*)(op + mf * 16) = acc[mf][nf];
            }
        }
    }
}

extern "C" void kernel_launch(void* const* d_in, const int* in_sizes, int n_in,
                              void* d_out, int out_size, void* d_ws, size_t ws_size,
                              hipStream_t stream) {
    const float* xy = (const float*)d_in[0];
    const float* C  = (const float*)d_in[1];
    const float* Tx = (const float*)d_in[2];
    const float* Ty = (const float*)d_in[3];
    float* out = (float*)d_out;

    int npts = in_sizes[0] / 2;
    int ntx  = in_sizes[2];
    int nty  = in_sizes[3];

    int pgs = (npts + NT * BPT - 1) / (NT * BPT);
    dim3 grid(pgs * 8);
    dim3 block(256);
    hipLaunchKernelGGL(spline_gemm, grid, block, 0, stream,
                       xy, C, Tx, Ty, out, npts, ntx, nty);
}